// Round 11
// baseline (1876.707 us; speedup 1.0000x reference)
//
#include <hip/hip_runtime.h>
#include <hip/hip_bf16.h>
#include <stdint.h>

#define B_ 64
#define T_ 512
#define I_ 1024
#define H_ 1024
#define BH (B_*H_)

typedef __attribute__((ext_vector_type(8))) short short8;
typedef __attribute__((ext_vector_type(4))) float f32x4;
typedef __attribute__((ext_vector_type(4))) unsigned u32x4;
typedef __attribute__((ext_vector_type(2))) unsigned u32x2;

static __device__ __forceinline__ unsigned short f2bf(float f) {
  union { float f; unsigned u; } v; v.f = f;
  unsigned r = v.u + 0x7fffu + ((v.u >> 16) & 1u);
  return (unsigned short)(r >> 16);
}

static __device__ __forceinline__ void glds16(const void* g, void* l) {
  __builtin_amdgcn_global_load_lds(
      (const __attribute__((address_space(1))) unsigned int*)g,
      (__attribute__((address_space(3))) unsigned int*)l, 16, 0, 0);
}

// ---------------- weight conversion f32 -> bf16 ----------------
__global__ void convert_weights(const f32x4* __restrict__ wih, const f32x4* __restrict__ whh,
                                uint2* __restrict__ wih_b, uint2* __restrict__ whh_b)
{
  int idx = blockIdx.x * blockDim.x + threadIdx.x;
  f32x4 a = wih[idx];
  uint2 o;
  o.x = f2bf(a[0]) | ((unsigned)f2bf(a[1]) << 16);
  o.y = f2bf(a[2]) | ((unsigned)f2bf(a[3]) << 16);
  wih_b[idx] = o;
  f32x4 b = whh[idx];
  uint2 p;
  p.x = f2bf(b[0]) | ((unsigned)f2bf(b[1]) << 16);
  p.y = f2bf(b[2]) | ((unsigned)f2bf(b[3]) << 16);
  whh_b[idx] = p;
}

// ---------------- x_proj GEMM (unchanged) ----------------
__launch_bounds__(256)
__global__ void gemm_xproj(const float* __restrict__ in,
                           const unsigned short* __restrict__ wb,
                           const float* __restrict__ bih,
                           const float* __restrict__ bhh,
                           float* __restrict__ out)
{
  __shared__ __align__(16) unsigned char As[16384];
  __shared__ __align__(16) unsigned char Bs[16384];
  const int tid = threadIdx.x;
  const int lane = tid & 63;
  const int w = tid >> 6;
  const int wm = w >> 1, wn = w & 1;
  const int bn = blockIdx.x, bm = blockIdx.y;

  const int ar = tid >> 1;
  const int ah = tid & 1;
  const int R0 = bm*128 + ar;
  const float* asrc = in + (size_t)(R0 & 63) * (T_*I_) + (size_t)(R0 >> 6) * I_ + ah*32;
  unsigned char* adst_base = As + ar*128;
  const int aswz_w = (ar & 7) << 4;

  f32x4 acc[4][4];
  #pragma unroll
  for (int i = 0; i < 4; ++i)
    #pragma unroll
    for (int j = 0; j < 4; ++j)
      acc[i][j] = (f32x4){0.f,0.f,0.f,0.f};

  f32x4 av[8];
  #pragma unroll
  for (int j = 0; j < 8; ++j) av[j] = *(const f32x4*)(asrc + 0*64 + j*4);

  for (int kt = 0; kt < 16; ++kt) {
    __syncthreads();
    #pragma unroll
    for (int q = 0; q < 4; ++q) {
      int inst = w*4 + q;
      int rb = inst*8 + (lane >> 3);
      int srcoff = ((bn*128 + rb) * I_ + kt*64) * 2 + (((lane & 7) * 16) ^ ((rb & 7) << 4));
      glds16((const unsigned char*)wb + srcoff, Bs + inst*1024);
    }
    #pragma unroll
    for (int j2 = 0; j2 < 4; ++j2) {
      uint4 val;
      f32x4 v0 = av[j2*2], v1 = av[j2*2+1];
      val.x = f2bf(v0[0]) | ((unsigned)f2bf(v0[1]) << 16);
      val.y = f2bf(v0[2]) | ((unsigned)f2bf(v0[3]) << 16);
      val.z = f2bf(v1[0]) | ((unsigned)f2bf(v1[1]) << 16);
      val.w = f2bf(v1[2]) | ((unsigned)f2bf(v1[3]) << 16);
      int koffb = ah*64 + j2*16;
      *(uint4*)(adst_base + (koffb ^ aswz_w)) = val;
    }
    __syncthreads();
    if (kt < 15) {
      #pragma unroll
      for (int j = 0; j < 8; ++j) av[j] = *(const f32x4*)(asrc + (kt+1)*64 + j*4);
    }
    #pragma unroll
    for (int kb = 0; kb < 2; ++kb) {
      const int kby = kb*64 + ((lane >> 4) << 4);
      short8 af[4], bfr[4];
      #pragma unroll
      for (int i = 0; i < 4; ++i) {
        int ra = wm*64 + i*16 + (lane & 15);
        af[i] = *(const short8*)(As + ra*128 + (kby ^ ((ra & 7) << 4)));
      }
      #pragma unroll
      for (int j = 0; j < 4; ++j) {
        int rb2 = wn*64 + j*16 + (lane & 15);
        bfr[j] = *(const short8*)(Bs + rb2*128 + (kby ^ ((rb2 & 7) << 4)));
      }
      #pragma unroll
      for (int i = 0; i < 4; ++i)
        #pragma unroll
        for (int j = 0; j < 4; ++j)
          acc[i][j] = __builtin_amdgcn_mfma_f32_16x16x32_bf16(af[i], bfr[j], acc[i][j], 0, 0, 0);
    }
  }
  #pragma unroll
  for (int j = 0; j < 4; ++j) {
    int col = bn*128 + wn*64 + j*16 + (lane & 15);
    float bias = bih[col] + bhh[col];
    #pragma unroll
    for (int i = 0; i < 4; ++i) {
      int Rb = bm*128 + wm*64 + i*16 + ((lane >> 4) << 2);
      #pragma unroll
      for (int q = 0; q < 4; ++q) {
        int R = Rb + q;
        out[(size_t)(R >> 6) * BH + (size_t)(R & 63) * H_ + col] = acc[i][j][q] + bias;
      }
    }
  }
}

// ---------------- recurrence: dual pipelined sweeps (A/B), counted vmcnt ----------------
// 64 WGs: gb=g>>4 (16 batch rows), gn=g&15 (64 H cols). Packet P = gn*256 + tid
// holds 4 bf16 + tag t+1, system-scope. Per step: sleep ~0.27us; issue sweep A;
// sleep ~0.21us; issue sweep B; drain vmcnt(16) -> check A; miss -> vmcnt(0) ->
// check B (0.3us newer snapshot); both miss -> proven re-sweep loop. Own slice
// (j==gn) bypasses global via the next-parity LDS tile.
__launch_bounds__(256, 1)
__global__ void rnn_recur(const unsigned short* __restrict__ whh_b,
                          float* __restrict__ out,
                          unsigned char* __restrict__ hx)
{
  extern __shared__ __align__(16) unsigned char lds[];
  const int tid = threadIdx.x;
  const int lane = tid & 63;
  const int w = tid >> 6;
  const int g = blockIdx.x;
  const int gb = g >> 4;
  const int gn = g & 15;

  // ---- one-time W_hh slice: global -> LDS (swizzled) -> registers ----
  for (int q = 0; q < 32; ++q) {
    int inst = w*32 + q;
    int nl = inst >> 1;
    int koff = (inst & 1)*1024 + lane*16;
    size_t srcoff = (size_t)(gn*64 + nl)*2048 + (size_t)(koff ^ ((nl & 7) << 4));
    glds16((const unsigned char*)whh_b + srcoff, lds + inst*1024);
  }
  asm volatile("s_waitcnt vmcnt(0)" ::: "memory");
  __syncthreads();

  const int arow = w*16 + (lane & 15);
  const unsigned char* wsrow = lds + (size_t)arow*2048;
  const int aswz = (arow & 7) << 4;
  const int klane = (lane >> 4) << 4;
  short8 af[32];
  #pragma unroll
  for (int kb = 0; kb < 32; ++kb)
    af[kb] = *(const short8*)(wsrow + ((kb*64 + klane) ^ aswz));
  __syncthreads();   // W region reused as hs double-buffer below

  const int bb = lane & 15;
  const int nq = (lane >> 4) << 2;
  const int colb = gn*64 + w*16 + nq;
  const int brow = gb*16 + bb;
  const int bswz = (bb & 7) << 4;

  // staging role
  const int srow = tid & 15;
  const int scol = tid >> 4;
  const int sswz = (srow & 7) << 4;

  f32x4 xp = *(const f32x4*)(out + (size_t)brow*H_ + colb);

  for (int t = 0; t < T_; ++t) {
    unsigned char* hsb = lds + (size_t)(t & 1)*32768;
    unsigned char* sdst = hsb + srow*2048;
    if (t == 0) {
      u32x2 z = (u32x2){0u, 0u};
      #pragma unroll
      for (int j = 0; j < 16; ++j)
        *(u32x2*)(sdst + (((j*16 + scol)*8) ^ sswz)) = z;
    } else {
      const unsigned want = (unsigned)t;
      const unsigned char* pb = hx + (size_t)(t & 1)*262144 + (size_t)gb*65536 + (size_t)tid*16;
      u32x4 a0,a1,a2,a3,a4,a5,a6,a7,a8,a9,a10,a11,a12,a13,a14,a15;
      u32x4 b0,b1,b2,b3,b4,b5,b6,b7,b8,b9,b10,b11,b12,b13,b14,b15;

      #define SWEEP_LO(r0,r1,r2,r3,r4,r5,r6,r7) \
        asm volatile( \
          "global_load_dwordx4 %0, %8, off sc0 sc1\n\t" \
          "global_load_dwordx4 %1, %9, off sc0 sc1\n\t" \
          "global_load_dwordx4 %2, %10, off sc0 sc1\n\t" \
          "global_load_dwordx4 %3, %11, off sc0 sc1\n\t" \
          "global_load_dwordx4 %4, %12, off sc0 sc1\n\t" \
          "global_load_dwordx4 %5, %13, off sc0 sc1\n\t" \
          "global_load_dwordx4 %6, %14, off sc0 sc1\n\t" \
          "global_load_dwordx4 %7, %15, off sc0 sc1" \
          : "=&v"(r0),"=&v"(r1),"=&v"(r2),"=&v"(r3),"=&v"(r4),"=&v"(r5),"=&v"(r6),"=&v"(r7) \
          : "v"(pb), "v"(pb+4096), "v"(pb+2*4096), "v"(pb+3*4096), \
            "v"(pb+4*4096), "v"(pb+5*4096), "v"(pb+6*4096), "v"(pb+7*4096) \
          : "memory");
      #define SWEEP_HI(r8,r9,r10,r11,r12,r13,r14,r15) \
        asm volatile( \
          "global_load_dwordx4 %0, %8, off sc0 sc1\n\t" \
          "global_load_dwordx4 %1, %9, off sc0 sc1\n\t" \
          "global_load_dwordx4 %2, %10, off sc0 sc1\n\t" \
          "global_load_dwordx4 %3, %11, off sc0 sc1\n\t" \
          "global_load_dwordx4 %4, %12, off sc0 sc1\n\t" \
          "global_load_dwordx4 %5, %13, off sc0 sc1\n\t" \
          "global_load_dwordx4 %6, %14, off sc0 sc1\n\t" \
          "global_load_dwordx4 %7, %15, off sc0 sc1" \
          : "=&v"(r8),"=&v"(r9),"=&v"(r10),"=&v"(r11),"=&v"(r12),"=&v"(r13),"=&v"(r14),"=&v"(r15) \
          : "v"(pb+8*4096), "v"(pb+9*4096), "v"(pb+10*4096), "v"(pb+11*4096), \
            "v"(pb+12*4096), "v"(pb+13*4096), "v"(pb+14*4096), "v"(pb+15*4096) \
          : "memory");
      #define DRAIN16(r0,r1,r2,r3,r4,r5,r6,r7,r8,r9,r10,r11,r12,r13,r14,r15,N) \
        asm volatile("s_waitcnt vmcnt(" #N ")" \
          : "+v"(r0),"+v"(r1),"+v"(r2),"+v"(r3),"+v"(r4),"+v"(r5),"+v"(r6),"+v"(r7), \
            "+v"(r8),"+v"(r9),"+v"(r10),"+v"(r11),"+v"(r12),"+v"(r13),"+v"(r14),"+v"(r15) \
          :: "memory");
      #define CHKSET(r0,r1,r2,r3,r4,r5,r6,r7,r8,r9,r10,r11,r12,r13,r14,r15,okv) { \
        okv = 1; \
        if (0 != gn && r0[2] != want) okv = 0;  if (1 != gn && r1[2] != want) okv = 0; \
        if (2 != gn && r2[2] != want) okv = 0;  if (3 != gn && r3[2] != want) okv = 0; \
        if (4 != gn && r4[2] != want) okv = 0;  if (5 != gn && r5[2] != want) okv = 0; \
        if (6 != gn && r6[2] != want) okv = 0;  if (7 != gn && r7[2] != want) okv = 0; \
        if (8 != gn && r8[2] != want) okv = 0;  if (9 != gn && r9[2] != want) okv = 0; \
        if (10 != gn && r10[2] != want) okv = 0; if (11 != gn && r11[2] != want) okv = 0; \
        if (12 != gn && r12[2] != want) okv = 0; if (13 != gn && r13[2] != want) okv = 0; \
        if (14 != gn && r14[2] != want) okv = 0; if (15 != gn && r15[2] != want) okv = 0; }
      #define STGSET(r0,r1,r2,r3,r4,r5,r6,r7,r8,r9,r10,r11,r12,r13,r14,r15) { \
        if (0 != gn)  *(u32x2*)(sdst + (((0*16 + scol)*8) ^ sswz))  = (u32x2){r0[0], r0[1]}; \
        if (1 != gn)  *(u32x2*)(sdst + (((1*16 + scol)*8) ^ sswz))  = (u32x2){r1[0], r1[1]}; \
        if (2 != gn)  *(u32x2*)(sdst + (((2*16 + scol)*8) ^ sswz))  = (u32x2){r2[0], r2[1]}; \
        if (3 != gn)  *(u32x2*)(sdst + (((3*16 + scol)*8) ^ sswz))  = (u32x2){r3[0], r3[1]}; \
        if (4 != gn)  *(u32x2*)(sdst + (((4*16 + scol)*8) ^ sswz))  = (u32x2){r4[0], r4[1]}; \
        if (5 != gn)  *(u32x2*)(sdst + (((5*16 + scol)*8) ^ sswz))  = (u32x2){r5[0], r5[1]}; \
        if (6 != gn)  *(u32x2*)(sdst + (((6*16 + scol)*8) ^ sswz))  = (u32x2){r6[0], r6[1]}; \
        if (7 != gn)  *(u32x2*)(sdst + (((7*16 + scol)*8) ^ sswz))  = (u32x2){r7[0], r7[1]}; \
        if (8 != gn)  *(u32x2*)(sdst + (((8*16 + scol)*8) ^ sswz))  = (u32x2){r8[0], r8[1]}; \
        if (9 != gn)  *(u32x2*)(sdst + (((9*16 + scol)*8) ^ sswz))  = (u32x2){r9[0], r9[1]}; \
        if (10 != gn) *(u32x2*)(sdst + (((10*16 + scol)*8) ^ sswz)) = (u32x2){r10[0], r10[1]}; \
        if (11 != gn) *(u32x2*)(sdst + (((11*16 + scol)*8) ^ sswz)) = (u32x2){r11[0], r11[1]}; \
        if (12 != gn) *(u32x2*)(sdst + (((12*16 + scol)*8) ^ sswz)) = (u32x2){r12[0], r12[1]}; \
        if (13 != gn) *(u32x2*)(sdst + (((13*16 + scol)*8) ^ sswz)) = (u32x2){r13[0], r13[1]}; \
        if (14 != gn) *(u32x2*)(sdst + (((14*16 + scol)*8) ^ sswz)) = (u32x2){r14[0], r14[1]}; \
        if (15 != gn) *(u32x2*)(sdst + (((15*16 + scol)*8) ^ sswz)) = (u32x2){r15[0], r15[1]}; }

      __builtin_amdgcn_s_sleep(10);          // ~0.27us: producer stores reach MALL
      SWEEP_LO(a0,a1,a2,a3,a4,a5,a6,a7)      // sweep A
      SWEEP_HI(a8,a9,a10,a11,a12,a13,a14,a15)
      __builtin_amdgcn_s_sleep(8);           // ~0.21us spacing
      SWEEP_LO(b0,b1,b2,b3,b4,b5,b6,b7)      // sweep B (newer snapshot)
      SWEEP_HI(b8,b9,b10,b11,b12,b13,b14,b15)
      DRAIN16(a0,a1,a2,a3,a4,a5,a6,a7,a8,a9,a10,a11,a12,a13,a14,a15,16)  // A done, B in flight
      int ok;
      CHKSET(a0,a1,a2,a3,a4,a5,a6,a7,a8,a9,a10,a11,a12,a13,a14,a15,ok)
      if (ok) {
        STGSET(a0,a1,a2,a3,a4,a5,a6,a7,a8,a9,a10,a11,a12,a13,a14,a15)
      } else {
        DRAIN16(b0,b1,b2,b3,b4,b5,b6,b7,b8,b9,b10,b11,b12,b13,b14,b15,0)
        CHKSET(b0,b1,b2,b3,b4,b5,b6,b7,b8,b9,b10,b11,b12,b13,b14,b15,ok)
        if (!ok) {
          for (;;) {
            __builtin_amdgcn_s_sleep(1);
            SWEEP_LO(b0,b1,b2,b3,b4,b5,b6,b7)
            SWEEP_HI(b8,b9,b10,b11,b12,b13,b14,b15)
            DRAIN16(b0,b1,b2,b3,b4,b5,b6,b7,b8,b9,b10,b11,b12,b13,b14,b15,0)
            CHKSET(b0,b1,b2,b3,b4,b5,b6,b7,b8,b9,b10,b11,b12,b13,b14,b15,ok)
            if (ok) break;
          }
        }
        STGSET(b0,b1,b2,b3,b4,b5,b6,b7,b8,b9,b10,b11,b12,b13,b14,b15)
      }
      #undef SWEEP_LO
      #undef SWEEP_HI
      #undef DRAIN16
      #undef CHKSET
      #undef STGSET
    }
    // single barrier per step: LDS-only drain (global stores/loads stay in flight)
    asm volatile("s_waitcnt lgkmcnt(0)\n\ts_barrier" ::: "memory");

    const unsigned char* hfrow = hsb + (size_t)bb*2048;
    f32x4 acc0 = (f32x4){0.f,0.f,0.f,0.f}, acc1 = (f32x4){0.f,0.f,0.f,0.f};
    #pragma unroll
    for (int kb = 0; kb < 32; kb += 2) {
      short8 w0 = *(const short8*)(hfrow + ((kb*64 + klane) ^ bswz));
      short8 w1 = *(const short8*)(hfrow + (((kb+1)*64 + klane) ^ bswz));
      acc0 = __builtin_amdgcn_mfma_f32_16x16x32_bf16(af[kb],   w0, acc0, 0, 0, 0);
      acc1 = __builtin_amdgcn_mfma_f32_16x16x32_bf16(af[kb+1], w1, acc1, 0, 0, 0);
    }
    f32x4 hval;
    #pragma unroll
    for (int q = 0; q < 4; ++q)
      hval[q] = tanhf(acc0[q] + acc1[q] + xp[q]);

    // tagged packet, fire-and-forget system-scope store
    u32x4 pkt;
    pkt[0] = f2bf(hval[0]) | ((unsigned)f2bf(hval[1]) << 16);
    pkt[1] = f2bf(hval[2]) | ((unsigned)f2bf(hval[3]) << 16);
    pkt[2] = (unsigned)(t + 1);
    pkt[3] = 0u;
    const unsigned char* wp = hx + (size_t)((t+1) & 1)*262144 + (size_t)gb*65536
                              + (size_t)(gn*256 + tid)*16;
    asm volatile("global_store_dwordx4 %0, %1, off sc0 sc1" :: "v"(wp), "v"(pkt) : "memory");

    // own slice straight into next-parity LDS tile (no global RT)
    unsigned char* hsn = lds + (size_t)((t+1) & 1)*32768;
    *(u32x2*)(hsn + (size_t)bb*2048 + ((colb*2) ^ bswz)) = (u32x2){pkt[0], pkt[1]};

    // f32 outputs (off the handshake path)
    *(f32x4*)(out + (size_t)t*BH + (size_t)brow*H_ + colb) = hval;
    if (t == T_-1)
      *(f32x4*)(out + (size_t)T_*BH + (size_t)brow*H_ + colb) = hval;

    int tn = (t < T_-1) ? t+1 : t;
    xp = *(const f32x4*)(out + (size_t)tn*BH + (size_t)brow*H_ + colb);
  }
}

extern "C" void kernel_launch(void* const* d_in, const int* in_sizes, int n_in,
                              void* d_out, int out_size, void* d_ws, size_t ws_size,
                              hipStream_t stream)
{
  const float* in  = (const float*)d_in[0];
  const float* wih = (const float*)d_in[1];
  const float* whh = (const float*)d_in[2];
  const float* bih = (const float*)d_in[3];
  const float* bhh = (const float*)d_in[4];
  float* out = (float*)d_out;
  unsigned char* ws = (unsigned char*)d_ws;

  unsigned char*  hx    = ws;                                   // 2 x 4 x 64KB tagged buffers
  unsigned short* wih_b = (unsigned short*)(ws + 524288);       // 2MB
  unsigned short* whh_b = (unsigned short*)(ws + 524288 + 2097152); // 2MB

  hipMemsetAsync(hx, 0, 524288, stream);   // clear stale tags (graph-replay safe)
  convert_weights<<<1024, 256, 0, stream>>>((const f32x4*)wih, (const f32x4*)whh,
                                            (uint2*)wih_b, (uint2*)whh_b);
  gemm_xproj<<<dim3(8, 256), 256, 0, stream>>>(in, wih_b, bih, bhh, out);
  rnn_recur<<<64, 256, 131072, stream>>>(whh_b, out, hx);
}